// Round 10
// baseline (177.242 us; speedup 1.0000x reference)
//
#include <hip/hip_runtime.h>

#define BATCH   16384
#define NF      1024
#define NWAVES  6144   // 768 blocks x 8 waves

// HIGH-OCCUPANCY PROBE (R9 diagnosis): every prior round ran ~7 waves/CU
// (OccupancyPercent 19-21% in ALL profiles) because W-in-regs (160 VGPR) or
// fat x-buffers capped residency. BW = bytes-in-flight / latency, and the
// 6.3 TB/s copy benchmark runs at 32 waves/CU. This round: W lives in LDS
// (40 KB/block, ds_read_b128 at 16B/lane stride = contiguous 1KB/wave,
// conflict-free, 40 compile-time offsets off ONE address register), no
// register W, no prefetch buffers -> ~70 live VGPR.
// __launch_bounds__(512,6) caps VGPR at 85 (live ~70, no R7-style spill)
// -> 3 blocks/CU x 8 waves = 24 waves/CU, 3x anything tested so far.

template <int CTRL>
__device__ __forceinline__ float dpp_add(float x) {
    int xi = __builtin_bit_cast(int, x);
    int yi = __builtin_amdgcn_update_dpp(xi, xi, CTRL, 0xf, 0xf, false);
    return x + __builtin_bit_cast(float, yi);
}

__device__ __forceinline__ float row_reduce_dpp(float x) {
    x = dpp_add<0xB1>(x);    // quad_perm [1,0,3,2]
    x = dpp_add<0x4E>(x);    // quad_perm [2,3,0,1] -> quad sums
    x = dpp_add<0x124>(x);   // row_ror:4
    x = dpp_add<0x128>(x);   // row_ror:8 -> 16-lane row sum in every lane
    return x;
}

__device__ __forceinline__ float wave_sum(float x) {
    float r = row_reduce_dpp(x);
    int ri = __builtin_bit_cast(int, r);
    float s0 = __builtin_bit_cast(float, __builtin_amdgcn_readlane(ri, 0));
    float s1 = __builtin_bit_cast(float, __builtin_amdgcn_readlane(ri, 16));
    float s2 = __builtin_bit_cast(float, __builtin_amdgcn_readlane(ri, 32));
    float s3 = __builtin_bit_cast(float, __builtin_amdgcn_readlane(ri, 48));
    return (s0 + s1) + (s2 + s3);
}

__global__ __launch_bounds__(512, 6)
void sdt_kernel(const float* __restrict__ x,
                const float* __restrict__ W,
                const float* __restrict__ b,
                const float* __restrict__ leaf,
                float* __restrict__ out)
{
    const int lane = threadIdx.x & 63;
    const int wid  = (int)(blockIdx.x) * 8 + (int)(threadIdx.x >> 6);

    // ---- W rows 0..9 staged to LDS (40 KB), coalesced float4 ----
    __shared__ float Ws[10 * NF];
    // ---- leaf table, transposed: lv_t[i*64 + l] = leaf[l*16 + i] ----
    __shared__ float lv_t[1024];

    for (int i = threadIdx.x; i < 10 * NF / 4; i += 512)
        reinterpret_cast<float4*>(Ws)[i] = reinterpret_cast<const float4*>(W)[i];

    if (threadIdx.x < 256) {
#pragma unroll
        for (int e = 0; e < 4; ++e) {
            int idx = threadIdx.x * 4 + e;
            lv_t[idx] = leaf[(idx & 63) * 16 + (idx >> 6)];
        }
    }

    float bias[10];
#pragma unroll
    for (int d = 0; d < 10; ++d) bias[d] = b[d];

    __syncthreads();

    // no barriers below: waves proceed independently (2-3 rows each)
    for (int row = wid; row < BATCH; row += NWAVES) {
        // ---- coalesced x loads: lane l reads float4 at 256k + 4l ----
        const float* xr = x + (size_t)row * NF;
        float4 xv[4];
#pragma unroll
        for (int k = 0; k < 4; ++k)
            xv[k] = *reinterpret_cast<const float4*>(xr + k * 256 + 4 * lane);

        // ---- 10 partial dots; W from LDS (one addr reg + imm offsets) ----
        float acc[10];
#pragma unroll
        for (int d = 0; d < 10; ++d) {
            float a = 0.0f;
#pragma unroll
            for (int k = 0; k < 4; ++k) {
                const float4 wv = *reinterpret_cast<const float4*>(
                    &Ws[d * NF + k * 256 + 4 * lane]);
                a = fmaf(xv[k].x, wv.x, a);
                a = fmaf(xv[k].y, wv.y, a);
                a = fmaf(xv[k].z, wv.z, a);
                a = fmaf(xv[k].w, wv.w, a);
            }
            acc[d] = a;
        }

        // ---- gates: wave-uniform z via DPP+readlane reduce (pure VALU) ----
        float g[10];
#pragma unroll
        for (int d = 0; d < 10; ++d) {
            float z = wave_sum(acc[d]) + bias[d];
            g[d] = __builtin_amdgcn_rcpf(1.0f + __expf(-z));
        }

        // ---- leaf DP: contract LSB (depth 9) upward; leaves from LDS ----
        float s9[8];
#pragma unroll
        for (int j = 0; j < 8; ++j) {
            float La = lv_t[(2 * j) * 64 + lane];
            float Lb = lv_t[(2 * j + 1) * 64 + lane];
            s9[j] = fmaf(g[9], Lb - La, La);
        }
        float s8[4];
#pragma unroll
        for (int j = 0; j < 4; ++j)
            s8[j] = fmaf(g[8], s9[2 * j + 1] - s9[2 * j], s9[2 * j]);
        float s7[2];
#pragma unroll
        for (int j = 0; j < 2; ++j)
            s7[j] = fmaf(g[7], s8[2 * j + 1] - s8[2 * j], s8[2 * j]);
        float s6 = fmaf(g[6], s7[1] - s7[0], s7[0]);

        // ---- per-lane 6-bit path weight (lane bits d=0..5, d=0 MSB) ----
        float w = 1.0f;
#pragma unroll
        for (int d = 0; d < 6; ++d) {
            int bit = (lane >> (5 - d)) & 1;
            w *= bit ? g[d] : (1.0f - g[d]);
        }

        // ---- weighted wave-sum; lane 0 stores ----
        float v = wave_sum(w * s6);
        if (lane == 0) out[row] = v;
    }
}

extern "C" void kernel_launch(void* const* d_in, const int* in_sizes, int n_in,
                              void* d_out, int out_size, void* d_ws, size_t ws_size,
                              hipStream_t stream) {
    const float* x    = (const float*)d_in[0];
    const float* W    = (const float*)d_in[1];
    const float* b    = (const float*)d_in[2];
    const float* leaf = (const float*)d_in[3];
    float* out = (float*)d_out;

    const int blocks  = 768;   // 3 blocks/CU x 8 waves = 24 waves/CU
    const int threads = 512;

    sdt_kernel<<<blocks, threads, 0, stream>>>(x, W, b, leaf, out);
}

// Round 11
// 53.719 us; speedup vs baseline: 3.2995x; 3.2995x over previous
//
#include <hip/hip_runtime.h>

#define BATCH   16384
#define NF      1024
#define NWAVES  6144   // 768 blocks x 8 waves

// CLEAN HIGH-OCCUPANCY PROBE (R10 retry).
// R10's __launch_bounds__(512,6) made the allocator cap at 40 VGPR (this
// compiler empirically targets 2x the declared waves/EU: (256,4)->64,
// (512,6)->40) and spill 240 MB. Retry with (512,3): cap ~84-170 VGPR,
// live set ~65-75 -> no spill, and LDS (44 KB/block) + VGPR allow
// 2-3 blocks/CU x 8 waves = 16-24 waves/CU — 2-3x every 26-µs round.
// W lives in LDS (ds_read_b128, contiguous per wave, 0 bank conflicts
// verified in R10); leaf table transposed in LDS; DPP+readlane reduces.

template <int CTRL>
__device__ __forceinline__ float dpp_add(float x) {
    int xi = __builtin_bit_cast(int, x);
    int yi = __builtin_amdgcn_update_dpp(xi, xi, CTRL, 0xf, 0xf, false);
    return x + __builtin_bit_cast(float, yi);
}

__device__ __forceinline__ float row_reduce_dpp(float x) {
    x = dpp_add<0xB1>(x);    // quad_perm [1,0,3,2]
    x = dpp_add<0x4E>(x);    // quad_perm [2,3,0,1] -> quad sums
    x = dpp_add<0x124>(x);   // row_ror:4
    x = dpp_add<0x128>(x);   // row_ror:8 -> 16-lane row sum in every lane
    return x;
}

__device__ __forceinline__ float wave_sum(float x) {
    float r = row_reduce_dpp(x);
    int ri = __builtin_bit_cast(int, r);
    float s0 = __builtin_bit_cast(float, __builtin_amdgcn_readlane(ri, 0));
    float s1 = __builtin_bit_cast(float, __builtin_amdgcn_readlane(ri, 16));
    float s2 = __builtin_bit_cast(float, __builtin_amdgcn_readlane(ri, 32));
    float s3 = __builtin_bit_cast(float, __builtin_amdgcn_readlane(ri, 48));
    return (s0 + s1) + (s2 + s3);
}

__global__ __launch_bounds__(512, 3)
void sdt_kernel(const float* __restrict__ x,
                const float* __restrict__ W,
                const float* __restrict__ b,
                const float* __restrict__ leaf,
                float* __restrict__ out)
{
    const int lane = threadIdx.x & 63;
    const int wid  = (int)(blockIdx.x) * 8 + (int)(threadIdx.x >> 6);

    // ---- W rows 0..9 staged to LDS (40 KB), coalesced float4 ----
    __shared__ float Ws[10 * NF];
    // ---- leaf table, transposed: lv_t[i*64 + l] = leaf[l*16 + i] ----
    __shared__ float lv_t[1024];

    for (int i = threadIdx.x; i < 10 * NF / 4; i += 512)
        reinterpret_cast<float4*>(Ws)[i] = reinterpret_cast<const float4*>(W)[i];

    if (threadIdx.x < 256) {
#pragma unroll
        for (int e = 0; e < 4; ++e) {
            int idx = threadIdx.x * 4 + e;
            lv_t[idx] = leaf[(idx & 63) * 16 + (idx >> 6)];
        }
    }

    float bias[10];
#pragma unroll
    for (int d = 0; d < 10; ++d) bias[d] = b[d];

    __syncthreads();

    // no barriers below: waves proceed independently (2-3 rows each)
    for (int row = wid; row < BATCH; row += NWAVES) {
        // ---- coalesced x loads: lane l reads float4 at 256k + 4l ----
        const float* xr = x + (size_t)row * NF;
        float4 xv[4];
#pragma unroll
        for (int k = 0; k < 4; ++k)
            xv[k] = *reinterpret_cast<const float4*>(xr + k * 256 + 4 * lane);

        // ---- 10 partial dots; W from LDS (one addr reg + imm offsets) ----
        float acc[10];
#pragma unroll
        for (int d = 0; d < 10; ++d) {
            float a = 0.0f;
#pragma unroll
            for (int k = 0; k < 4; ++k) {
                const float4 wv = *reinterpret_cast<const float4*>(
                    &Ws[d * NF + k * 256 + 4 * lane]);
                a = fmaf(xv[k].x, wv.x, a);
                a = fmaf(xv[k].y, wv.y, a);
                a = fmaf(xv[k].z, wv.z, a);
                a = fmaf(xv[k].w, wv.w, a);
            }
            acc[d] = a;
        }

        // ---- gates: wave-uniform z via DPP+readlane reduce (pure VALU) ----
        float g[10];
#pragma unroll
        for (int d = 0; d < 10; ++d) {
            float z = wave_sum(acc[d]) + bias[d];
            g[d] = __builtin_amdgcn_rcpf(1.0f + __expf(-z));
        }

        // ---- leaf DP: contract LSB (depth 9) upward; leaves from LDS ----
        float s9[8];
#pragma unroll
        for (int j = 0; j < 8; ++j) {
            float La = lv_t[(2 * j) * 64 + lane];
            float Lb = lv_t[(2 * j + 1) * 64 + lane];
            s9[j] = fmaf(g[9], Lb - La, La);
        }
        float s8[4];
#pragma unroll
        for (int j = 0; j < 4; ++j)
            s8[j] = fmaf(g[8], s9[2 * j + 1] - s9[2 * j], s9[2 * j]);
        float s7[2];
#pragma unroll
        for (int j = 0; j < 2; ++j)
            s7[j] = fmaf(g[7], s8[2 * j + 1] - s8[2 * j], s8[2 * j]);
        float s6 = fmaf(g[6], s7[1] - s7[0], s7[0]);

        // ---- per-lane 6-bit path weight (lane bits d=0..5, d=0 MSB) ----
        float w = 1.0f;
#pragma unroll
        for (int d = 0; d < 6; ++d) {
            int bit = (lane >> (5 - d)) & 1;
            w *= bit ? g[d] : (1.0f - g[d]);
        }

        // ---- weighted wave-sum; lane 0 stores ----
        float v = wave_sum(w * s6);
        if (lane == 0) out[row] = v;
    }
}

extern "C" void kernel_launch(void* const* d_in, const int* in_sizes, int n_in,
                              void* d_out, int out_size, void* d_ws, size_t ws_size,
                              hipStream_t stream) {
    const float* x    = (const float*)d_in[0];
    const float* W    = (const float*)d_in[1];
    const float* b    = (const float*)d_in[2];
    const float* leaf = (const float*)d_in[3];
    float* out = (float*)d_out;

    const int blocks  = 768;   // up to 3 blocks/CU (LDS 44KB) x 8 waves
    const int threads = 512;

    sdt_kernel<<<blocks, threads, 0, stream>>>(x, W, b, leaf, out);
}

// Round 12
// 28.595 us; speedup vs baseline: 6.1984x; 1.8786x over previous
//
#include <hip/hip_runtime.h>

#define BATCH    16384
#define NF       1024
#define NWAVES1  2048   // phase 1: 512 blocks x 4 waves
#define NWAVES2  4096   // phase 2: 1024 blocks x 4 waves

// TWO-KERNEL SPLIT (decisive experiment after R1-R11's invariant 26-µs floor).
// Phase 1 (sdt_logits): memcpy-shaped streamer. W pinned in AGPRs (R9 trick,
// spill-free), per row: 4 float4 loads -> 40 FMA -> 4-step DPP group-reduce
// -> 4 lanes store 40 partial sums (bias/4 folded in). No readlane broadcast,
// no sigmoid, no leaf DP, no long serial tail -> nothing to throttle the
// stream. Partials go to d_ws (16384 x 40 floats = 2.6 MB).
// Phase 2 (sdt_combine): wave-per-row; 40-lane coalesced partial load,
// quad DPP sum, 10 readlane broadcasts, sigmoid, leaf DP, path weight,
// wave sum, store. ~2 µs total.

template <int CTRL>
__device__ __forceinline__ float dpp_add(float x) {
    int xi = __builtin_bit_cast(int, x);
    int yi = __builtin_amdgcn_update_dpp(xi, xi, CTRL, 0xf, 0xf, false);
    return x + __builtin_bit_cast(float, yi);
}

// sum over each 16-lane group (result in every lane of the group)
__device__ __forceinline__ float group16_reduce(float x) {
    x = dpp_add<0xB1>(x);    // quad_perm [1,0,3,2]
    x = dpp_add<0x4E>(x);    // quad_perm [2,3,0,1] -> quad sums
    x = dpp_add<0x124>(x);   // row_ror:4
    x = dpp_add<0x128>(x);   // row_ror:8 -> 16-lane group sum
    return x;
}

__device__ __forceinline__ float wave_sum(float x) {
    float r = group16_reduce(x);
    int ri = __builtin_bit_cast(int, r);
    float s0 = __builtin_bit_cast(float, __builtin_amdgcn_readlane(ri, 0));
    float s1 = __builtin_bit_cast(float, __builtin_amdgcn_readlane(ri, 16));
    float s2 = __builtin_bit_cast(float, __builtin_amdgcn_readlane(ri, 32));
    float s3 = __builtin_bit_cast(float, __builtin_amdgcn_readlane(ri, 48));
    return (s0 + s1) + (s2 + s3);
}

// ---------------- phase 1: streaming logit partials ----------------
__global__ __launch_bounds__(256, 2)
void sdt_logits(const float* __restrict__ x,
                const float* __restrict__ W,
                const float* __restrict__ b,
                float* __restrict__ part)   // [BATCH][10][4]
{
    const int lane = threadIdx.x & 63;
    const int wid  = (int)((blockIdx.x * blockDim.x + threadIdx.x) >> 6);

    // W slices pinned in regs (AGPR via unified file): zero W re-read traffic.
    float4 Wr[10][4];
#pragma unroll
    for (int d = 0; d < 10; ++d)
#pragma unroll
        for (int k = 0; k < 4; ++k)
            Wr[d][k] = *reinterpret_cast<const float4*>(W + d * NF + k * 256 + 4 * lane);
#pragma unroll
    for (int d = 0; d < 10; ++d)
#pragma unroll
        for (int k = 0; k < 4; ++k)
            asm volatile("" : "+v"(Wr[d][k].x), "+v"(Wr[d][k].y),
                              "+v"(Wr[d][k].z), "+v"(Wr[d][k].w));

    float bq[10];   // bias/4, folded into each of the 4 group partials
#pragma unroll
    for (int d = 0; d < 10; ++d) bq[d] = b[d] * 0.25f;

    auto load_row = [&](float4 (&dst)[4], int r) {
        const float* xr = x + (size_t)r * NF;
#pragma unroll
        for (int k = 0; k < 4; ++k)
            dst[k] = *reinterpret_cast<const float4*>(xr + k * 256 + 4 * lane);
    };

    auto process_row = [&](const float4 (&xv)[4], int row) {
        float acc[10];
#pragma unroll
        for (int d = 0; d < 10; ++d) {
            float a = 0.0f;
#pragma unroll
            for (int k = 0; k < 4; ++k) {
                a = fmaf(xv[k].x, Wr[d][k].x, a);
                a = fmaf(xv[k].y, Wr[d][k].y, a);
                a = fmaf(xv[k].z, Wr[d][k].z, a);
                a = fmaf(xv[k].w, Wr[d][k].w, a);
            }
            acc[d] = a;
        }
        // 4-step DPP reduce per d; partial per 16-lane group. No broadcast,
        // no sigmoid, no DP — the store is the only consumer.
        float* pr = part + (size_t)row * 40 + (lane >> 4);
        const bool st = (lane & 15) == 0;
#pragma unroll
        for (int d = 0; d < 10; ++d) {
            float r = group16_reduce(acc[d]) + bq[d];
            if (st) pr[d * 4] = r;
        }
    };

    // 8 rows per wave, 3-buffer rolling pipeline (prefetch depth 2)
    float4 xb0[4], xb1[4], xb2[4];
    load_row(xb0, wid);
    load_row(xb1, wid + 1 * NWAVES1);

    load_row(xb2, wid + 2 * NWAVES1); process_row(xb0, wid);
    load_row(xb0, wid + 3 * NWAVES1); process_row(xb1, wid + 1 * NWAVES1);
    load_row(xb1, wid + 4 * NWAVES1); process_row(xb2, wid + 2 * NWAVES1);
    load_row(xb2, wid + 5 * NWAVES1); process_row(xb0, wid + 3 * NWAVES1);
    load_row(xb0, wid + 6 * NWAVES1); process_row(xb1, wid + 4 * NWAVES1);
    load_row(xb1, wid + 7 * NWAVES1); process_row(xb2, wid + 5 * NWAVES1);
    process_row(xb0, wid + 6 * NWAVES1);
    process_row(xb1, wid + 7 * NWAVES1);
}

// ---------------- phase 2: combine -> sigmoid -> leaf DP -> out ----------------
__global__ __launch_bounds__(256, 2)
void sdt_combine(const float* __restrict__ part,
                 const float* __restrict__ leaf,
                 float* __restrict__ out)
{
    const int lane = threadIdx.x & 63;
    const int wid  = (int)((blockIdx.x * blockDim.x + threadIdx.x) >> 6);

    // leaf table, transposed: lv_t[i*64 + l] = leaf[l*16 + i]
    __shared__ float lv_t[1024];
#pragma unroll
    for (int e = 0; e < 4; ++e) {
        int idx = threadIdx.x * 4 + e;
        lv_t[idx] = leaf[(idx & 63) * 16 + (idx >> 6)];
    }
    __syncthreads();

    for (int row = wid; row < BATCH; row += NWAVES2) {
        // 40 partials, coalesced (lanes 0..39); z_d = sum of quad 4d..4d+3
        float p = 0.0f;
        if (lane < 40) p = part[(size_t)row * 40 + lane];
        p = dpp_add<0xB1>(p);
        p = dpp_add<0x4E>(p);   // quad sums: z_d complete in lanes 4d..4d+3

        int pi = __builtin_bit_cast(int, p);
        float g[10];
#pragma unroll
        for (int d = 0; d < 10; ++d) {
            float z = __builtin_bit_cast(float, __builtin_amdgcn_readlane(pi, 4 * d));
            g[d] = __builtin_amdgcn_rcpf(1.0f + __expf(-z));
        }

        // leaf DP: contract LSB (depth 9) upward
        float s9[8];
#pragma unroll
        for (int j = 0; j < 8; ++j) {
            float La = lv_t[(2 * j) * 64 + lane];
            float Lb = lv_t[(2 * j + 1) * 64 + lane];
            s9[j] = fmaf(g[9], Lb - La, La);
        }
        float s8[4];
#pragma unroll
        for (int j = 0; j < 4; ++j)
            s8[j] = fmaf(g[8], s9[2 * j + 1] - s9[2 * j], s9[2 * j]);
        float s7[2];
#pragma unroll
        for (int j = 0; j < 2; ++j)
            s7[j] = fmaf(g[7], s8[2 * j + 1] - s8[2 * j], s8[2 * j]);
        float s6 = fmaf(g[6], s7[1] - s7[0], s7[0]);

        float w = 1.0f;
#pragma unroll
        for (int d = 0; d < 6; ++d) {
            int bit = (lane >> (5 - d)) & 1;
            w *= bit ? g[d] : (1.0f - g[d]);
        }

        float v = wave_sum(w * s6);
        if (lane == 0) out[row] = v;
    }
}

extern "C" void kernel_launch(void* const* d_in, const int* in_sizes, int n_in,
                              void* d_out, int out_size, void* d_ws, size_t ws_size,
                              hipStream_t stream) {
    const float* x    = (const float*)d_in[0];
    const float* W    = (const float*)d_in[1];
    const float* b    = (const float*)d_in[2];
    const float* leaf = (const float*)d_in[3];
    float* out  = (float*)d_out;
    float* part = (float*)d_ws;   // 16384 * 40 * 4 B = 2.62 MB

    sdt_logits<<<512, 256, 0, stream>>>(x, W, b, part);
    sdt_combine<<<1024, 256, 0, stream>>>(part, leaf, out);
}